// Round 3
// baseline (37.241 us; speedup 1.0000x reference)
//
#include <hip/hip_runtime.h>
#include <hip/hip_bf16.h>
#include <float.h>

#define BB 128
#define SS 4096
#define TT 48
#define EE 10

__device__ __forceinline__ int rfl(int x) { return __builtin_amdgcn_readfirstlane(x); }

// ---------------------------------------------------------------------------
// ws layout:
//   [0     .. vocab)   unsigned char safe[vocab]   (fully rewritten each call)
//   [65536 .. +25MB)   fallback backpointers       (touched only on fallback)
// ---------------------------------------------------------------------------

// Kernel V: one wave per vocab token. safe[tok]=1 iff the Viterbi argmax row
// out of the canonical state c (c_j = em_j + b_j + trans[0][j]) is all-O:
//   for all j: max_{i>=1}(c_i + trans[i][j]) <= c_0 + trans[0][j]  (margin .25)
// Exact 48x48 check, 4 split max-chains.
__global__ __launch_bounds__(256) void k_vocab(
    const float* __restrict__ emb, const float* __restrict__ W,
    const float* __restrict__ bias, const float* __restrict__ trans,
    unsigned char* __restrict__ safe, int vocab)
{
  const int lane = threadIdx.x & 63;
  const int tok = rfl(blockIdx.x * 4 + (threadIdx.x >> 6));
  if (tok >= vocab) return;
  const int jj = lane < TT ? lane : TT - 1;

  const float t0j = trans[jj];
  float x = bias[jj] + t0j;
  const float* er = emb + (size_t)tok * EE;   // uniform address -> scalar loads
#pragma unroll
  for (int d = 0; d < EE; ++d) x = fmaf(er[d], W[jj * EE + d], x);
  const float x0 = __shfl(x, 0, 64);

  float m0 = -FLT_MAX, m1 = -FLT_MAX, m2 = -FLT_MAX, m3 = -FLT_MAX;
#pragma unroll
  for (int i = 1; i < TT; i += 4) {
    m0 = fmaxf(m0, __shfl(x, i, 64) + trans[i * TT + jj]);
    if (i + 1 < TT) m1 = fmaxf(m1, __shfl(x, i + 1, 64) + trans[(i + 1) * TT + jj]);
    if (i + 2 < TT) m2 = fmaxf(m2, __shfl(x, i + 2, 64) + trans[(i + 2) * TT + jj]);
    if (i + 3 < TT) m3 = fmaxf(m3, __shfl(x, i + 3, 64) + trans[(i + 3) * TT + jj]);
  }
  const float mx = fmaxf(fmaxf(m0, m1), fmaxf(m2, m3));
  const bool ok = (lane >= TT) ? true : (mx <= x0 + t0j - 0.25f);
  const int s = __all(ok) ? 1 : 0;
  if (lane == 0) safe[tok] = (unsigned char)s;
}

// Kernel R: one block (256 threads) per batch row.
//  - all threads: zero-fill the row, gather safe[] for interior positions,
//    OR failure into LDS
//  - wave 0: exact t=0 check (start bias) + final-tag argmax
//  - if clean: write final tag, done. Else: wave 0 runs the exact sequential
//    reference Viterbi (shfl-based, backpointers in ws) for this row.
__global__ __launch_bounds__(256) void k_row(
    const int* __restrict__ tok_ids, const float* __restrict__ emb,
    const float* __restrict__ W, const float* __restrict__ bias,
    const float* __restrict__ start_t, const float* __restrict__ end_t,
    const float* __restrict__ trans, const unsigned char* __restrict__ safe,
    int* __restrict__ out, unsigned char* __restrict__ bp_all)
{
  __shared__ int s_fail;
  const int b = blockIdx.x;
  const int tid = threadIdx.x;
  if (tid == 0) s_fail = 0;
  __syncthreads();

  // ---- zero-fill + safe-gather (16 positions per thread) ----
  const int4* trow = (const int4*)(tok_ids + b * SS);
  int4* orow = (int4*)(out + b * SS);
  int fail = 0;
#pragma unroll
  for (int q = 0; q < 4; ++q) {
    const int4 tk = trow[tid * 4 + q];
    orow[tid * 4 + q] = make_int4(0, 0, 0, 0);
    const int p = tid * 16 + q * 4;
    fail |= (p != 0      && !safe[tk.x]);
    fail |=                 !safe[tk.y];
    fail |=                 !safe[tk.z];
    fail |= (p + 3 != SS - 1 && !safe[tk.w]);
  }
  if (fail) atomicOr(&s_fail, 1);
  __syncthreads();

  // ---- wave 0: t=0 exact check + final tag ----
  const int lane = tid;
  const int jj = (lane & 63) < TT ? (lane & 63) : TT - 1;
  int final_tag = 0;
  if (tid < 64) {
    {
      const int tk0 = tok_ids[b * SS];
      float x = bias[jj] + start_t[jj];
      const float* er = emb + (size_t)tk0 * EE;
#pragma unroll
      for (int d = 0; d < EE; ++d) x = fmaf(er[d], W[jj * EE + d], x);
      const float x0 = __shfl(x, 0, 64);
      float m0 = -FLT_MAX, m1 = -FLT_MAX, m2 = -FLT_MAX, m3 = -FLT_MAX;
#pragma unroll
      for (int i = 1; i < TT; i += 4) {
        m0 = fmaxf(m0, __shfl(x, i, 64) + trans[i * TT + jj]);
        if (i + 1 < TT) m1 = fmaxf(m1, __shfl(x, i + 1, 64) + trans[(i + 1) * TT + jj]);
        if (i + 2 < TT) m2 = fmaxf(m2, __shfl(x, i + 2, 64) + trans[(i + 2) * TT + jj]);
        if (i + 3 < TT) m3 = fmaxf(m3, __shfl(x, i + 3, 64) + trans[(i + 3) * TT + jj]);
      }
      const float mx = fmaxf(fmaxf(m0, m1), fmaxf(m2, m3));
      const bool ok = (lane >= TT) ? true : (mx <= x0 + trans[jj] - 0.25f);
      if (!__all(ok) && lane == 0) s_fail = 1;
    }
    {
      const int tkL = tok_ids[b * SS + SS - 1];
      float y = bias[jj] + trans[jj] + end_t[jj];
      const float* er = emb + (size_t)tkL * EE;
#pragma unroll
      for (int d = 0; d < EE; ++d) y = fmaf(er[d], W[jj * EE + d], y);
      if (lane >= TT) y = -FLT_MAX;
      int idx = lane;
#pragma unroll
      for (int m = 32; m; m >>= 1) {
        const float oy = __shfl_xor(y, m, 64);
        const int oi = __shfl_xor(idx, m, 64);
        if (oy > y || (oy == y && oi < idx)) { y = oy; idx = oi; }
      }
      final_tag = idx;  // valid in lane 0
    }
  }
  __syncthreads();

  if (s_fail == 0) {
    if (tid == 0) out[b * SS + (SS - 1)] = final_tag;
    return;
  }

  // ---- exact sequential fallback (reference semantics), wave 0 only ----
  if (tid >= 64) return;
  unsigned char* __restrict__ bp = bp_all + (size_t)b * (SS - 1) * TT;
  float sc;
  {
    const int tk = tok_ids[b * SS];
    float em = bias[jj];
    const float* er = emb + (size_t)tk * EE;
#pragma unroll
    for (int d = 0; d < EE; ++d) em = fmaf(er[d], W[jj * EE + d], em);
    sc = start_t[jj] + em;
  }
  for (int t = 1; t < SS; ++t) {
    const int tk = tok_ids[b * SS + t];
    float em = bias[jj];
    const float* er = emb + (size_t)tk * EE;
#pragma unroll
    for (int d = 0; d < EE; ++d) em = fmaf(er[d], W[jj * EE + d], em);
    float best = -FLT_MAX; int bpi = 0;
#pragma unroll 1
    for (int i = 0; i < TT; ++i) {
      const float v = (__shfl(sc, i, 64) + trans[i * TT + jj]) + em;
      if (v > best) { best = v; bpi = i; }
    }
    if (lane < TT) bp[(size_t)(t - 1) * TT + lane] = (unsigned char)bpi;
    sc = best;
  }
  {
    float y = sc + end_t[jj];
    if (lane >= TT) y = -FLT_MAX;
    int idx = lane;
#pragma unroll
    for (int m = 32; m; m >>= 1) {
      const float oy = __shfl_xor(y, m, 64);
      const int oi = __shfl_xor(idx, m, 64);
      if (oy > y || (oy == y && oi < idx)) { y = oy; idx = oi; }
    }
    if (lane == 0) {
      int curtag = idx;
      out[b * SS + (SS - 1)] = curtag;
      for (int t = SS - 2; t >= 0; --t) {
        curtag = bp[(size_t)t * TT + curtag];
        out[b * SS + t] = curtag;
      }
    }
  }
}

extern "C" void kernel_launch(void* const* d_in, const int* in_sizes, int n_in,
                              void* d_out, int out_size, void* d_ws, size_t ws_size,
                              hipStream_t stream) {
  const int*   tok_ids = (const int*)d_in[0];
  const float* emb     = (const float*)d_in[1];
  const float* W       = (const float*)d_in[2];
  const float* bias    = (const float*)d_in[3];
  const float* start_t = (const float*)d_in[4];
  const float* end_t   = (const float*)d_in[5];
  const float* trans   = (const float*)d_in[6];
  int* out = (int*)d_out;

  const int vocab = in_sizes[1] / EE;
  unsigned char* safe = (unsigned char*)d_ws;
  unsigned char* bp   = (unsigned char*)d_ws + 65536;

  k_vocab<<<(vocab + 3) / 4, 256, 0, stream>>>(emb, W, bias, trans, safe, vocab);
  k_row<<<BB, 256, 0, stream>>>(tok_ids, emb, W, bias, start_t, end_t, trans,
                                safe, out, bp);
}

// Round 4
// 21.492 us; speedup vs baseline: 1.7328x; 1.7328x over previous
//
#include <hip/hip_runtime.h>
#include <hip/hip_bf16.h>
#include <float.h>

#define BB 128
#define SS 4096
#define TT 48
#define EE 10
#define TPW 4   // tokens per wave in k_vocab

__device__ __forceinline__ int rfl(int x) { return __builtin_amdgcn_readfirstlane(x); }

// ---------------------------------------------------------------------------
// ws layout:
//   [0      .. 65536)  unsigned char safe[vocab]
//   [65536  .. +512 )  int flags[128]
//   [66048  .. +192 )  float rowC[48]
//   [131072 .. +25MB)  fallback backpointers (touched only on fallback)
//
// rowC[i] = max_j(trans[i][j] - trans[0][j]) + 1e-3  is state-independent:
// for ANY state x, (forall i: x_i + rowC[i] <= x_0)  =>  the Viterbi argmax
// row out of x is all-O (tag 0), with margin absorbing f32 rounding. A
// spurious failure only flags the row -> exact fallback, never wrongness.
// ---------------------------------------------------------------------------

// Kernel V: 16 tokens per 256-thread block (4 per wave). Wave 0 computes rowC
// from the L1-resident 9KB trans table; block 0 publishes rowC + clears flags.
__global__ __launch_bounds__(256) void k_vocab(
    const float* __restrict__ emb, const float* __restrict__ W,
    const float* __restrict__ bias, const float* __restrict__ trans,
    unsigned char* __restrict__ safe, int* __restrict__ flags,
    float* __restrict__ rowC_g, int vocab)
{
  __shared__ float rowC[TT];
  const int tid = threadIdx.x;
  const int lane = tid & 63;
  const int wv = tid >> 6;

  if (tid < TT) {
    float acc = -FLT_MAX;
#pragma unroll 1
    for (int j = 0; j < TT; ++j)
      acc = fmaxf(acc, trans[tid * TT + j] - trans[j]);
    rowC[tid] = acc + 1e-3f;
  }
  __syncthreads();

  if (blockIdx.x == 0) {
    if (tid < BB) flags[tid] = 0;
    if (tid < TT) rowC_g[tid] = rowC[tid];
  }

  const int jj = lane < TT ? lane : TT - 1;
  const float rc = rowC[jj];
  float w[EE];
#pragma unroll
  for (int d = 0; d < EE; ++d) w[d] = W[jj * EE + d];
  const float base = bias[jj] + trans[jj];   // bias + trans[0][j]

  const int tok0 = rfl(blockIdx.x * (4 * TPW) + wv * TPW);
#pragma unroll
  for (int k = 0; k < TPW; ++k) {
    const int tok = tok0 + k;                // wave-uniform
    if (tok < vocab) {
      const float* er = emb + (size_t)tok * EE;  // uniform -> scalar loads
      float x = base;
#pragma unroll
      for (int d = 0; d < EE; ++d) x = fmaf(er[d], w[d], x);
      const float x0 = __shfl(x, 0, 64);
      const bool ok = (lane == 0 || lane >= TT) ? true : (x + rc <= x0);
      const int s = __all(ok) ? 1 : 0;
      if (lane == 0) safe[tok] = (unsigned char)s;
    }
  }
}

// Kernel B: 4 blocks per batch row, 1 int4 (4 positions) per thread.
// Zero-fill + safe-gather + flag aggregation; chunk-0 wave 0 does the exact
// t=0 check (start bias); chunk-3 wave 3 computes the final tag and thread
// 255 stores it fused into its int4.
__global__ __launch_bounds__(256) void k_body(
    const int* __restrict__ tok_ids, const float* __restrict__ emb,
    const float* __restrict__ W, const float* __restrict__ bias,
    const float* __restrict__ start_t, const float* __restrict__ end_t,
    const float* __restrict__ trans, const unsigned char* __restrict__ safe,
    const float* __restrict__ rowC_g, int* __restrict__ out,
    int* __restrict__ flags)
{
  const int bid = blockIdx.x;
  const int b = bid >> 2, chunk = bid & 3;
  const int tid = threadIdx.x;
  const int p0 = chunk * 1024 + tid * 4;     // position of .x within the row

  const int4 tk = *(const int4*)(tok_ids + b * SS + p0);
  int fail = 0;
  if (p0 != 0)          fail |= !safe[tk.x];
  fail |= !safe[tk.y];
  fail |= !safe[tk.z];
  if (p0 + 3 != SS - 1) fail |= !safe[tk.w];
  if (fail) atomicOr(&flags[b], 1);

  const int lane = tid & 63;
  const int jj = lane < TT ? lane : TT - 1;
  int wtag = 0;

  if (chunk == 0 && tid < 64) {
    // exact t=0 check: state uses start bias; rowC test is state-independent
    const int tkA = tok_ids[b * SS];
    const float* er = emb + (size_t)tkA * EE;
    float x = bias[jj] + start_t[jj];
#pragma unroll
    for (int d = 0; d < EE; ++d) x = fmaf(er[d], W[jj * EE + d], x);
    const float x0 = __shfl(x, 0, 64);
    const float rc = rowC_g[jj];
    const bool ok = (lane == 0 || lane >= TT) ? true : (x + rc <= x0);
    if (!__all(ok) && lane == 0) atomicOr(&flags[b], 1);
  }

  if (chunk == 3 && tid >= 192) {
    // wave 3: final tag = argmax_j( em + b + trans[0][j] + end[j] ), ties->low j
    const int tkL = tok_ids[b * SS + SS - 1];
    const float* er = emb + (size_t)tkL * EE;
    float y = bias[jj] + trans[jj] + end_t[jj];
#pragma unroll
    for (int d = 0; d < EE; ++d) y = fmaf(er[d], W[jj * EE + d], y);
    if (lane >= TT) y = -FLT_MAX;
    int idx = lane;
#pragma unroll
    for (int m = 32; m; m >>= 1) {
      const float oy = __shfl_xor(y, m, 64);
      const int oi = __shfl_xor(idx, m, 64);
      if (oy > y || (oy == y && oi < idx)) { y = oy; idx = oi; }
    }
    wtag = idx;  // valid in every lane after full butterfly
  }

  int4 z = make_int4(0, 0, 0, 0);
  if (chunk == 3 && tid == 255) z.w = wtag;
  *(int4*)(out + b * SS + p0) = z;
}

// Kernel F: exact sequential fallback (reference semantics), early-exit.
__global__ __launch_bounds__(64) void k_fallback(
    const int* __restrict__ tok_ids, const float* __restrict__ emb,
    const float* __restrict__ W, const float* __restrict__ bias,
    const float* __restrict__ start_t, const float* __restrict__ end_t,
    const float* __restrict__ trans, int* __restrict__ out,
    const int* __restrict__ flags, unsigned char* __restrict__ bp_all)
{
  const int b = blockIdx.x;
  if (flags[b] == 0) return;

  const int lane = threadIdx.x;
  const int jj = lane < TT ? lane : TT - 1;
  unsigned char* __restrict__ bp = bp_all + (size_t)b * (SS - 1) * TT;
  float w[EE];
#pragma unroll
  for (int d = 0; d < EE; ++d) w[d] = W[jj * EE + d];
  const float bj = bias[jj];

  float sc;
  {
    const int tk = tok_ids[b * SS];
    const float* er = emb + (size_t)tk * EE;
    float em = bj;
#pragma unroll
    for (int d = 0; d < EE; ++d) em = fmaf(er[d], w[d], em);
    sc = start_t[jj] + em;
  }
  for (int t = 1; t < SS; ++t) {
    const int tk = tok_ids[b * SS + t];
    const float* er = emb + (size_t)tk * EE;
    float em = bj;
#pragma unroll
    for (int d = 0; d < EE; ++d) em = fmaf(er[d], w[d], em);
    float best = -FLT_MAX; int bpi = 0;
#pragma unroll 1
    for (int i = 0; i < TT; ++i) {
      const float v = (__shfl(sc, i, 64) + trans[i * TT + jj]) + em;
      if (v > best) { best = v; bpi = i; }
    }
    if (lane < TT) bp[(size_t)(t - 1) * TT + lane] = (unsigned char)bpi;
    sc = best;
  }
  {
    float y = sc + end_t[jj];
    if (lane >= TT) y = -FLT_MAX;
    int idx = lane;
#pragma unroll
    for (int m = 32; m; m >>= 1) {
      const float oy = __shfl_xor(y, m, 64);
      const int oi = __shfl_xor(idx, m, 64);
      if (oy > y || (oy == y && oi < idx)) { y = oy; idx = oi; }
    }
    if (lane == 0) {
      int curtag = idx;
      out[b * SS + (SS - 1)] = curtag;
      for (int t = SS - 2; t >= 0; --t) {
        curtag = bp[(size_t)t * TT + curtag];
        out[b * SS + t] = curtag;
      }
    }
  }
}

extern "C" void kernel_launch(void* const* d_in, const int* in_sizes, int n_in,
                              void* d_out, int out_size, void* d_ws, size_t ws_size,
                              hipStream_t stream) {
  const int*   tok_ids = (const int*)d_in[0];
  const float* emb     = (const float*)d_in[1];
  const float* W       = (const float*)d_in[2];
  const float* bias    = (const float*)d_in[3];
  const float* start_t = (const float*)d_in[4];
  const float* end_t   = (const float*)d_in[5];
  const float* trans   = (const float*)d_in[6];
  int* out = (int*)d_out;

  const int vocab = in_sizes[1] / EE;
  unsigned char* safe  = (unsigned char*)d_ws;
  int*           flags = (int*)((char*)d_ws + 65536);
  float*         rowC  = (float*)((char*)d_ws + 66048);
  unsigned char* bp    = (unsigned char*)d_ws + 131072;

  const int tok_per_block = 4 * TPW;  // 16
  k_vocab<<<(vocab + tok_per_block - 1) / tok_per_block, 256, 0, stream>>>(
      emb, W, bias, trans, safe, flags, rowC, vocab);
  k_body<<<BB * 4, 256, 0, stream>>>(tok_ids, emb, W, bias, start_t, end_t,
                                     trans, safe, rowC, out, flags);
  k_fallback<<<BB, 64, 0, stream>>>(tok_ids, emb, W, bias, start_t, end_t,
                                    trans, out, flags, bp);
}